// Round 5
// baseline (381.595 us; speedup 1.0000x reference)
//
#include <hip/hip_runtime.h>
#include <hip/hip_bf16.h>

#define T_TOKENS 2048
#define NE 8
#define HID 1024
#define INTER_ 2048
#define NPAIR (T_TOKENS * 2)

typedef unsigned short u16;
typedef __attribute__((ext_vector_type(4))) float f32x4;
typedef __attribute__((ext_vector_type(8))) short s16x8;

__device__ __forceinline__ u16 f2b(float f) {
    union { float f; unsigned u; } v; v.f = f;
    unsigned r = v.u + 0x7fffu + ((v.u >> 16) & 1u);
    return (u16)(r >> 16);
}

// async global->LDS, 16B per lane; LDS dest is wave-uniform base + lane*16
__device__ __forceinline__ void gl_lds16(const u16* g, u16* l) {
    __builtin_amdgcn_global_load_lds(
        (const __attribute__((address_space(1))) unsigned int*)g,
        (__attribute__((address_space(3))) unsigned int*)l, 16, 0, 0);
}

// ---------------- routing: top2 + softmax + grouped scatter, one block ----------------
__global__ __launch_bounds__(256) void route_all(const float* __restrict__ logits,
                                                 int* __restrict__ offs,
                                                 int* __restrict__ pair_tok,
                                                 float* __restrict__ pair_w,
                                                 int* __restrict__ pair_slot,
                                                 float* __restrict__ tokW) {
    __shared__ int s_cnt[NE];
    __shared__ int s_cur[NE];
    __shared__ short s_e0[T_TOKENS];
    __shared__ short s_e1[T_TOKENS];
    __shared__ float s_w0[T_TOKENS];
    int tid = threadIdx.x;
    if (tid < NE) s_cnt[tid] = 0;
    __syncthreads();
    for (int t = tid; t < T_TOKENS; t += 256) {
        float l[NE];
#pragma unroll
        for (int i = 0; i < NE; i++) l[i] = logits[t * NE + i];
        int i0 = 0; float m0 = l[0];
#pragma unroll
        for (int i = 1; i < NE; i++) if (l[i] > m0) { m0 = l[i]; i0 = i; }
        int i1 = -1; float m1 = -1e30f;
#pragma unroll
        for (int i = 0; i < NE; i++) if (i != i0 && l[i] > m1) { m1 = l[i]; i1 = i; }
        float w0 = 1.f / (1.f + __expf(m1 - m0));
        s_e0[t] = (short)i0; s_e1[t] = (short)i1; s_w0[t] = w0;
        atomicAdd(&s_cnt[i0], 1);
        atomicAdd(&s_cnt[i1], 1);
    }
    __syncthreads();
    if (tid == 0) {
        int a = 0;
        for (int e = 0; e < NE; e++) { offs[e] = a; s_cur[e] = a; a += s_cnt[e]; }
        offs[NE] = a;
    }
    __syncthreads();
    for (int t = tid; t < T_TOKENS; t += 256) {
        int i0 = s_e0[t], i1 = s_e1[t];
        float w0 = s_w0[t];
        int sl0 = atomicAdd(&s_cur[i0], 1);
        pair_tok[sl0] = t; pair_w[sl0] = w0;
        pair_slot[2 * t] = sl0; tokW[2 * t] = w0;
        int sl1 = atomicAdd(&s_cur[i1], 1);
        pair_tok[sl1] = t; pair_w[sl1] = 1.f - w0;
        pair_slot[2 * t + 1] = sl1; tokW[2 * t + 1] = 1.f - w0;
    }
}

// ---------------- fp32 -> bf16 convert of x ----------------
__global__ void cvt_x_kernel(const float* __restrict__ x, u16* __restrict__ xb) {
    int i = blockIdx.x * 256 + threadIdx.x;
    float4 v = ((const float4*)x)[i];
    ushort4 b;
    b.x = f2b(v.x); b.y = f2b(v.y); b.z = f2b(v.z); b.w = f2b(v.w);
    ((ushort4*)xb)[i] = b;
}

// ---------------- all-weights transpose+convert: W[e][K][N] f32 -> Wt[e][N][K] bf16 ----------------
// 128x128 tiles. Phase1: per instr 2 k-rows x 512B contiguous reads, in-register 4x4
// micro-transpose, ushort4 LDS writes. Phase2: per instr 4 n-rows x 256B fully
// contiguous uint4 stores (full lines, long DRAM-row runs on both sides).
__global__ __launch_bounds__(256) void transpose_all(const float* __restrict__ wi0,
                                                     const float* __restrict__ wi1,
                                                     const float* __restrict__ wo,
                                                     u16* __restrict__ wt0,
                                                     u16* __restrict__ wt1,
                                                     u16* __restrict__ wto) {
    int wsel = blockIdx.y >> 3, e = blockIdx.y & 7;
    const float* W; u16* Wt; int K, N, nb, kb;
    int bx = blockIdx.x;
    if (wsel == 0)      { W = wi0; Wt = wt0; }
    else if (wsel == 1) { W = wi1; Wt = wt1; }
    else                { W = wo;  Wt = wto; }
    if (wsel < 2) { K = HID; N = INTER_; nb = (bx & 15) * 128; kb = (bx >> 4) * 128; }
    else          { K = INTER_; N = HID; nb = (bx & 7) * 128; kb = (bx >> 3) * 128; }
    const float* Win = W + (size_t)e * K * N;
    u16* Wout = Wt + (size_t)e * N * K;
    __shared__ __align__(16) u16 tile[128 * 128];   // [n][k], 32 KB
    int tid = threadIdx.x;
    {
        int n4 = (tid & 31) * 4;
        int k4 = (tid >> 5) * 4;
#pragma unroll
        for (int b = 0; b < 4; b++) {
            int k = k4 + 32 * b;
            float4 v[4];
#pragma unroll
            for (int j = 0; j < 4; j++)
                v[j] = *(const float4*)&Win[(size_t)(kb + k + j) * N + nb + n4];
#pragma unroll
            for (int i = 0; i < 4; i++) {
                ushort4 o;
                o.x = f2b(((const float*)&v[0])[i]);
                o.y = f2b(((const float*)&v[1])[i]);
                o.z = f2b(((const float*)&v[2])[i]);
                o.w = f2b(((const float*)&v[3])[i]);
                *(ushort4*)&tile[(n4 + i) * 128 + k] = o;
            }
        }
    }
    __syncthreads();
    {
        int c = tid & 15;          // 16B chunk within row (16 chunks = 256B row)
        int nB = tid >> 4;
#pragma unroll
        for (int p = 0; p < 8; p++) {
            int n = nB + 16 * p;
            uint4 v = *(const uint4*)&tile[n * 128 + c * 8];
            *(uint4*)&Wout[(size_t)(nb + n) * K + kb + c * 8] = v;
        }
    }
}

// ---------------- fused up-proj: intr = silu(x@wi0) * (x@wi1) ----------------
// BK=64, XOR-8 source swizzle so fragment ds_read_b128s are conflict-free.
__global__ __launch_bounds__(256, 3) void fused_up_kernel(
        const u16* __restrict__ A, const u16* __restrict__ B0t, const u16* __restrict__ B1t,
        const int* __restrict__ pair_tok, const int* __restrict__ offs,
        u16* __restrict__ intr) {
    int e = blockIdx.z;
    int off = offs[e];
    int cnt = offs[e + 1] - off;
    int row0 = blockIdx.y * 128;
    if (row0 >= cnt) return;
    int nt = blockIdx.x * 128;

    __shared__ __align__(16) u16 As[128 * 64];
    __shared__ __align__(16) u16 Bs0[128 * 64];
    __shared__ __align__(16) u16 Bs1[128 * 64];

    int tid = threadIdx.x;
    int wave = tid >> 6, lane = tid & 63;

    const u16 *gA[4], *gB0[4], *gB1[4];
    u16 *lA[4], *lB0[4], *lB1[4];
    const size_t eNK = (size_t)e * INTER_ * HID;
#pragma unroll
    for (int is = 0; is < 4; is++) {
        int c = wave * 4 + is;
        int r = c * 8 + (lane >> 3);
        int sg = (lane & 7) ^ (r & 7);
        int mr = row0 + r; if (mr > cnt - 1) mr = cnt - 1;
        int arow = pair_tok[off + mr];
        gA[is]  = A + (size_t)arow * HID + sg * 8;
        gB0[is] = B0t + eNK + (size_t)(nt + r) * HID + sg * 8;
        gB1[is] = B1t + eNK + (size_t)(nt + r) * HID + sg * 8;
        lA[is]  = As  + c * 512;
        lB0[is] = Bs0 + c * 512;
        lB1[is] = Bs1 + c * 512;
    }

    int wr = (wave >> 1) * 64, wc = (wave & 1) * 64;
    int fm = lane & 15, quad = lane >> 4;

    f32x4 acc0[4][4], acc1[4][4];
#pragma unroll
    for (int i = 0; i < 4; i++)
#pragma unroll
        for (int j = 0; j < 4; j++) {
            acc0[i][j] = (f32x4){0.f, 0.f, 0.f, 0.f};
            acc1[i][j] = (f32x4){0.f, 0.f, 0.f, 0.f};
        }

    for (int kb = 0; kb < HID; kb += 64) {
#pragma unroll
        for (int is = 0; is < 4; is++) {
            gl_lds16(gA[is] + kb, lA[is]);
            gl_lds16(gB0[is] + kb, lB0[is]);
            gl_lds16(gB1[is] + kb, lB1[is]);
        }
        __syncthreads();
#pragma unroll
        for (int step = 0; step < 2; step++) {
            int f = step * 4 + quad;
            s16x8 af[4];
#pragma unroll
            for (int i = 0; i < 4; i++) {
                int R = wr + i * 16 + fm;
                af[i] = *(const s16x8*)&As[R * 64 + ((f ^ (R & 7)) * 8)];
            }
#pragma unroll
            for (int j = 0; j < 4; j++) {
                int R = wc + j * 16 + fm;
                s16x8 b0 = *(const s16x8*)&Bs0[R * 64 + ((f ^ (R & 7)) * 8)];
                s16x8 b1 = *(const s16x8*)&Bs1[R * 64 + ((f ^ (R & 7)) * 8)];
#pragma unroll
                for (int i = 0; i < 4; i++) {
                    acc0[i][j] = __builtin_amdgcn_mfma_f32_16x16x32_bf16(af[i], b0, acc0[i][j], 0, 0, 0);
                    acc1[i][j] = __builtin_amdgcn_mfma_f32_16x16x32_bf16(af[i], b1, acc1[i][j], 0, 0, 0);
                }
            }
        }
        __syncthreads();
    }

    int r4 = quad * 4, cc = lane & 15;
#pragma unroll
    for (int i = 0; i < 4; i++) {
#pragma unroll
        for (int reg = 0; reg < 4; reg++) {
            int rr = wr + i * 16 + r4 + reg;
            if (row0 + rr < cnt) {
                size_t slot = (size_t)(off + row0 + rr);
#pragma unroll
                for (int j = 0; j < 4; j++) {
                    int col = nt + wc + j * 16 + cc;
                    float a = acc0[i][j][reg];
                    float b = acc1[i][j][reg];
                    float s = a / (1.f + __expf(-a)) * b;
                    intr[slot * INTER_ + col] = f2b(s);
                }
            }
        }
    }
}

// ---------------- down-proj: ypart[ks] = intr @ wo (split-K=2, plain stores) ----------------
__global__ __launch_bounds__(256, 3) void down_kernel(
        const u16* __restrict__ A, const u16* __restrict__ Bt,
        const int* __restrict__ offs, float* __restrict__ ypart) {
    int e = blockIdx.z >> 1, ks = blockIdx.z & 1;
    int off = offs[e];
    int cnt = offs[e + 1] - off;
    int row0 = blockIdx.y * 128;
    if (row0 >= cnt) return;
    int nt = blockIdx.x * 128;

    __shared__ __align__(16) u16 As[128 * 64];
    __shared__ __align__(16) u16 Bs[128 * 64];

    int tid = threadIdx.x;
    int wave = tid >> 6, lane = tid & 63;

    const u16 *gA[4], *gB[4];
    u16 *lA[4], *lB[4];
    const size_t eNK = (size_t)e * HID * INTER_;
#pragma unroll
    for (int is = 0; is < 4; is++) {
        int c = wave * 4 + is;
        int r = c * 8 + (lane >> 3);
        int sg = (lane & 7) ^ (r & 7);
        int mr = row0 + r; if (mr > cnt - 1) mr = cnt - 1;
        gA[is] = A + (size_t)(off + mr) * INTER_ + sg * 8;
        gB[is] = Bt + eNK + (size_t)(nt + r) * INTER_ + sg * 8;
        lA[is] = As + c * 512;
        lB[is] = Bs + c * 512;
    }

    int wr = (wave >> 1) * 64, wc = (wave & 1) * 64;
    int fm = lane & 15, quad = lane >> 4;

    f32x4 acc[4][4];
#pragma unroll
    for (int i = 0; i < 4; i++)
#pragma unroll
        for (int j = 0; j < 4; j++) acc[i][j] = (f32x4){0.f, 0.f, 0.f, 0.f};

    int kend = ks * 1024 + 1024;
    for (int kb = ks * 1024; kb < kend; kb += 64) {
#pragma unroll
        for (int is = 0; is < 4; is++) {
            gl_lds16(gA[is] + kb, lA[is]);
            gl_lds16(gB[is] + kb, lB[is]);
        }
        __syncthreads();
#pragma unroll
        for (int step = 0; step < 2; step++) {
            int f = step * 4 + quad;
            s16x8 af[4], bfr[4];
#pragma unroll
            for (int i = 0; i < 4; i++) {
                int R = wr + i * 16 + fm;
                af[i] = *(const s16x8*)&As[R * 64 + ((f ^ (R & 7)) * 8)];
            }
#pragma unroll
            for (int j = 0; j < 4; j++) {
                int R = wc + j * 16 + fm;
                bfr[j] = *(const s16x8*)&Bs[R * 64 + ((f ^ (R & 7)) * 8)];
            }
#pragma unroll
            for (int i = 0; i < 4; i++)
#pragma unroll
                for (int j = 0; j < 4; j++)
                    acc[i][j] = __builtin_amdgcn_mfma_f32_16x16x32_bf16(af[i], bfr[j], acc[i][j], 0, 0, 0);
        }
        __syncthreads();
    }

    int r4 = quad * 4, cc = lane & 15;
    float* yout = ypart + (size_t)ks * NPAIR * HID;
#pragma unroll
    for (int i = 0; i < 4; i++) {
#pragma unroll
        for (int reg = 0; reg < 4; reg++) {
            int rr = wr + i * 16 + r4 + reg;
            if (row0 + rr < cnt) {
                size_t slot = (size_t)(off + row0 + rr);
#pragma unroll
                for (int j = 0; j < 4; j++) {
                    int col = nt + wc + j * 16 + cc;
                    yout[slot * HID + col] = acc[i][j][reg];
                }
            }
        }
    }
}

// ---------------- weighted combine (sums the two split-K partials) ----------------
__global__ void combine_kernel(const float* __restrict__ y0, const float* __restrict__ y1,
                               const int* __restrict__ pair_slot,
                               const float* __restrict__ tokW, float* __restrict__ out) {
    int i = blockIdx.x * 256 + threadIdx.x;
    int t = i >> 8;
    int h4 = i & 255;
    int s0 = pair_slot[2 * t], s1 = pair_slot[2 * t + 1];
    float w0 = tokW[2 * t], w1 = tokW[2 * t + 1];
    float4 a0 = ((const float4*)y0)[(size_t)s0 * 256 + h4];
    float4 a1 = ((const float4*)y1)[(size_t)s0 * 256 + h4];
    float4 b0 = ((const float4*)y0)[(size_t)s1 * 256 + h4];
    float4 b1 = ((const float4*)y1)[(size_t)s1 * 256 + h4];
    float4 r;
    r.x = w0 * (a0.x + a1.x) + w1 * (b0.x + b1.x);
    r.y = w0 * (a0.y + a1.y) + w1 * (b0.y + b1.y);
    r.z = w0 * (a0.z + a1.z) + w1 * (b0.z + b1.z);
    r.w = w0 * (a0.w + a1.w) + w1 * (b0.w + b1.w);
    ((float4*)out)[i] = r;
}

extern "C" void kernel_launch(void* const* d_in, const int* in_sizes, int n_in,
                              void* d_out, int out_size, void* d_ws, size_t ws_size,
                              hipStream_t stream) {
    (void)in_sizes; (void)n_in; (void)out_size; (void)ws_size;
    const float* x   = (const float*)d_in[0];
    const float* rl  = (const float*)d_in[1];
    const float* wi0 = (const float*)d_in[2];
    const float* wi1 = (const float*)d_in[3];
    const float* wo  = (const float*)d_in[4];
    float* out = (float*)d_out;

    char* p = (char*)d_ws;
    auto alloc = [&](size_t bytes) -> void* {
        void* r = (void*)p;
        p += (bytes + 255) & ~(size_t)255;
        return r;
    };
    u16* xb   = (u16*)alloc((size_t)T_TOKENS * HID * 2);          // 4 MB
    u16* wt0  = (u16*)alloc((size_t)NE * HID * INTER_ * 2);       // 32 MB  [E][I][H]
    u16* wt1  = (u16*)alloc((size_t)NE * HID * INTER_ * 2);       // 32 MB
    u16* wto  = (u16*)alloc((size_t)NE * HID * INTER_ * 2);       // 32 MB  [E][H][I]
    u16* intr = (u16*)alloc((size_t)NPAIR * INTER_ * 2);          // 16 MB
    float* ypart = (float*)alloc((size_t)2 * NPAIR * HID * 4);    // 32 MB
    int* offs     = (int*)alloc((NE + 1) * sizeof(int));
    int* pair_tok = (int*)alloc(NPAIR * sizeof(int));
    float* pair_w = (float*)alloc(NPAIR * sizeof(float));
    int* pair_slot= (int*)alloc(NPAIR * sizeof(int));
    float* tokW   = (float*)alloc(NPAIR * sizeof(float));

    route_all<<<1, 256, 0, stream>>>(rl, offs, pair_tok, pair_w, pair_slot, tokW);
    cvt_x_kernel<<<T_TOKENS * HID / 4 / 256, 256, 0, stream>>>(x, xb);
    transpose_all<<<dim3(128, 24), 256, 0, stream>>>(wi0, wi1, wo, wt0, wt1, wto);

    dim3 g1(INTER_ / 128, 16, NE);
    fused_up_kernel<<<g1, 256, 0, stream>>>(xb, wt0, wt1, pair_tok, offs, intr);
    dim3 g2(HID / 128, 16, NE * 2);
    down_kernel<<<g2, 256, 0, stream>>>(intr, wto, offs, ypart);
    combine_kernel<<<T_TOKENS * HID / 4 / 256, 256, 0, stream>>>(
        ypart, ypart + (size_t)NPAIR * HID, pair_slot, tokW, out);
}

// Round 6
// 328.363 us; speedup vs baseline: 1.1621x; 1.1621x over previous
//
#include <hip/hip_runtime.h>
#include <hip/hip_bf16.h>

#define T_TOKENS 2048
#define NE 8
#define HID 1024
#define INTER_ 2048
#define NPAIR (T_TOKENS * 2)

typedef unsigned short u16;
typedef __attribute__((ext_vector_type(4))) float f32x4;
typedef __attribute__((ext_vector_type(8))) short s16x8;

__device__ __forceinline__ u16 f2b(float f) {
    union { float f; unsigned u; } v; v.f = f;
    unsigned r = v.u + 0x7fffu + ((v.u >> 16) & 1u);
    return (u16)(r >> 16);
}

// async global->LDS, 16B per lane; LDS dest is wave-uniform base + lane*16
__device__ __forceinline__ void gl_lds16(const u16* g, u16* l) {
    __builtin_amdgcn_global_load_lds(
        (const __attribute__((address_space(1))) unsigned int*)g,
        (__attribute__((address_space(3))) unsigned int*)l, 16, 0, 0);
}

// ---------------- routing: top2 + softmax + grouped scatter, one block ----------------
__global__ __launch_bounds__(256) void route_all(const float* __restrict__ logits,
                                                 int* __restrict__ offs,
                                                 int* __restrict__ pair_tok,
                                                 float* __restrict__ pair_w,
                                                 int* __restrict__ pair_slot,
                                                 float* __restrict__ tokW) {
    __shared__ int s_cnt[NE];
    __shared__ int s_cur[NE];
    __shared__ short s_e0[T_TOKENS];
    __shared__ short s_e1[T_TOKENS];
    __shared__ float s_w0[T_TOKENS];
    int tid = threadIdx.x;
    if (tid < NE) s_cnt[tid] = 0;
    __syncthreads();
    for (int t = tid; t < T_TOKENS; t += 256) {
        float l[NE];
#pragma unroll
        for (int i = 0; i < NE; i++) l[i] = logits[t * NE + i];
        int i0 = 0; float m0 = l[0];
#pragma unroll
        for (int i = 1; i < NE; i++) if (l[i] > m0) { m0 = l[i]; i0 = i; }
        int i1 = -1; float m1 = -1e30f;
#pragma unroll
        for (int i = 0; i < NE; i++) if (i != i0 && l[i] > m1) { m1 = l[i]; i1 = i; }
        float w0 = 1.f / (1.f + __expf(m1 - m0));
        s_e0[t] = (short)i0; s_e1[t] = (short)i1; s_w0[t] = w0;
        atomicAdd(&s_cnt[i0], 1);
        atomicAdd(&s_cnt[i1], 1);
    }
    __syncthreads();
    if (tid == 0) {
        int a = 0;
        for (int e = 0; e < NE; e++) { offs[e] = a; s_cur[e] = a; a += s_cnt[e]; }
        offs[NE] = a;
    }
    __syncthreads();
    for (int t = tid; t < T_TOKENS; t += 256) {
        int i0 = s_e0[t], i1 = s_e1[t];
        float w0 = s_w0[t];
        int sl0 = atomicAdd(&s_cur[i0], 1);
        pair_tok[sl0] = t; pair_w[sl0] = w0;
        pair_slot[2 * t] = sl0; tokW[2 * t] = w0;
        int sl1 = atomicAdd(&s_cur[i1], 1);
        pair_tok[sl1] = t; pair_w[sl1] = 1.f - w0;
        pair_slot[2 * t + 1] = sl1; tokW[2 * t + 1] = 1.f - w0;
    }
}

// ---------------- fp32 -> bf16 convert of x ----------------
__global__ void cvt_x_kernel(const float* __restrict__ x, u16* __restrict__ xb) {
    int i = blockIdx.x * 256 + threadIdx.x;
    float4 v = ((const float4*)x)[i];
    ushort4 b;
    b.x = f2b(v.x); b.y = f2b(v.y); b.z = f2b(v.z); b.w = f2b(v.w);
    ((ushort4*)xb)[i] = b;
}

// ---------------- all-weights transpose+convert: W[e][K][N] f32 -> Wt[e][N][K] bf16 ----------------
// 128x128 tiles: long contiguous DRAM runs on both read (512B/row) and write (256B/row).
__global__ __launch_bounds__(256) void transpose_all(const float* __restrict__ wi0,
                                                     const float* __restrict__ wi1,
                                                     const float* __restrict__ wo,
                                                     u16* __restrict__ wt0,
                                                     u16* __restrict__ wt1,
                                                     u16* __restrict__ wto) {
    int wsel = blockIdx.y >> 3, e = blockIdx.y & 7;
    const float* W; u16* Wt; int K, N, nb, kb;
    int bx = blockIdx.x;
    if (wsel == 0)      { W = wi0; Wt = wt0; }
    else if (wsel == 1) { W = wi1; Wt = wt1; }
    else                { W = wo;  Wt = wto; }
    if (wsel < 2) { K = HID; N = INTER_; nb = (bx & 15) * 128; kb = (bx >> 4) * 128; }
    else          { K = INTER_; N = HID; nb = (bx & 7) * 128; kb = (bx >> 3) * 128; }
    const float* Win = W + (size_t)e * K * N;
    u16* Wout = Wt + (size_t)e * N * K;
    __shared__ __align__(16) u16 tile[128 * 128];   // [n][k], 32 KB
    int tid = threadIdx.x;
    {
        int n4 = (tid & 31) * 4;
        int k4 = (tid >> 5) * 4;
#pragma unroll
        for (int b = 0; b < 4; b++) {
            int k = k4 + 32 * b;
            float4 v[4];
#pragma unroll
            for (int j = 0; j < 4; j++)
                v[j] = *(const float4*)&Win[(size_t)(kb + k + j) * N + nb + n4];
#pragma unroll
            for (int i = 0; i < 4; i++) {
                ushort4 o;
                o.x = f2b(((const float*)&v[0])[i]);
                o.y = f2b(((const float*)&v[1])[i]);
                o.z = f2b(((const float*)&v[2])[i]);
                o.w = f2b(((const float*)&v[3])[i]);
                *(ushort4*)&tile[(n4 + i) * 128 + k] = o;
            }
        }
    }
    __syncthreads();
    {
        int c = tid & 15;          // 16B chunk within row (16 chunks = 256B row)
        int nB = tid >> 4;
#pragma unroll
        for (int p = 0; p < 8; p++) {
            int n = nB + 16 * p;
            uint4 v = *(const uint4*)&tile[n * 128 + c * 8];
            *(uint4*)&Wout[(size_t)(nb + n) * K + kb + c * 8] = v;
        }
    }
}

// ---------------- fused up-proj: intr = silu(x@wi0) * (x@wi1) ----------------
// BK=64, XOR-8 source swizzle so fragment ds_read_b128s are conflict-free.
// launch_bounds(256,2): (256,3) caps VGPRs at ~170 and spills the 128 acc regs
// to scratch (~83 MB HBM write traffic, 115 us vs 68) — measured round 5.
__global__ __launch_bounds__(256, 2) void fused_up_kernel(
        const u16* __restrict__ A, const u16* __restrict__ B0t, const u16* __restrict__ B1t,
        const int* __restrict__ pair_tok, const int* __restrict__ offs,
        u16* __restrict__ intr) {
    int e = blockIdx.z;
    int off = offs[e];
    int cnt = offs[e + 1] - off;
    int row0 = blockIdx.y * 128;
    if (row0 >= cnt) return;
    int nt = blockIdx.x * 128;

    __shared__ __align__(16) u16 As[128 * 64];
    __shared__ __align__(16) u16 Bs0[128 * 64];
    __shared__ __align__(16) u16 Bs1[128 * 64];

    int tid = threadIdx.x;
    int wave = tid >> 6, lane = tid & 63;

    const u16 *gA[4], *gB0[4], *gB1[4];
    u16 *lA[4], *lB0[4], *lB1[4];
    const size_t eNK = (size_t)e * INTER_ * HID;
#pragma unroll
    for (int is = 0; is < 4; is++) {
        int c = wave * 4 + is;
        int r = c * 8 + (lane >> 3);
        int sg = (lane & 7) ^ (r & 7);
        int mr = row0 + r; if (mr > cnt - 1) mr = cnt - 1;
        int arow = pair_tok[off + mr];
        gA[is]  = A + (size_t)arow * HID + sg * 8;
        gB0[is] = B0t + eNK + (size_t)(nt + r) * HID + sg * 8;
        gB1[is] = B1t + eNK + (size_t)(nt + r) * HID + sg * 8;
        lA[is]  = As  + c * 512;
        lB0[is] = Bs0 + c * 512;
        lB1[is] = Bs1 + c * 512;
    }

    int wr = (wave >> 1) * 64, wc = (wave & 1) * 64;
    int fm = lane & 15, quad = lane >> 4;

    f32x4 acc0[4][4], acc1[4][4];
#pragma unroll
    for (int i = 0; i < 4; i++)
#pragma unroll
        for (int j = 0; j < 4; j++) {
            acc0[i][j] = (f32x4){0.f, 0.f, 0.f, 0.f};
            acc1[i][j] = (f32x4){0.f, 0.f, 0.f, 0.f};
        }

    for (int kb = 0; kb < HID; kb += 64) {
#pragma unroll
        for (int is = 0; is < 4; is++) {
            gl_lds16(gA[is] + kb, lA[is]);
            gl_lds16(gB0[is] + kb, lB0[is]);
            gl_lds16(gB1[is] + kb, lB1[is]);
        }
        __syncthreads();
#pragma unroll
        for (int step = 0; step < 2; step++) {
            int f = step * 4 + quad;
            s16x8 af[4];
#pragma unroll
            for (int i = 0; i < 4; i++) {
                int R = wr + i * 16 + fm;
                af[i] = *(const s16x8*)&As[R * 64 + ((f ^ (R & 7)) * 8)];
            }
#pragma unroll
            for (int j = 0; j < 4; j++) {
                int R = wc + j * 16 + fm;
                s16x8 b0 = *(const s16x8*)&Bs0[R * 64 + ((f ^ (R & 7)) * 8)];
                s16x8 b1 = *(const s16x8*)&Bs1[R * 64 + ((f ^ (R & 7)) * 8)];
#pragma unroll
                for (int i = 0; i < 4; i++) {
                    acc0[i][j] = __builtin_amdgcn_mfma_f32_16x16x32_bf16(af[i], b0, acc0[i][j], 0, 0, 0);
                    acc1[i][j] = __builtin_amdgcn_mfma_f32_16x16x32_bf16(af[i], b1, acc1[i][j], 0, 0, 0);
                }
            }
        }
        __syncthreads();
    }

    int r4 = quad * 4, cc = lane & 15;
#pragma unroll
    for (int i = 0; i < 4; i++) {
#pragma unroll
        for (int reg = 0; reg < 4; reg++) {
            int rr = wr + i * 16 + r4 + reg;
            if (row0 + rr < cnt) {
                size_t slot = (size_t)(off + row0 + rr);
#pragma unroll
                for (int j = 0; j < 4; j++) {
                    int col = nt + wc + j * 16 + cc;
                    float a = acc0[i][j][reg];
                    float b = acc1[i][j][reg];
                    float s = a / (1.f + __expf(-a)) * b;
                    intr[slot * INTER_ + col] = f2b(s);
                }
            }
        }
    }
}

// ---------------- down-proj: ypart[ks] = intr @ wo (split-K=2, plain stores) ----------------
__global__ __launch_bounds__(256, 2) void down_kernel(
        const u16* __restrict__ A, const u16* __restrict__ Bt,
        const int* __restrict__ offs, float* __restrict__ ypart) {
    int e = blockIdx.z >> 1, ks = blockIdx.z & 1;
    int off = offs[e];
    int cnt = offs[e + 1] - off;
    int row0 = blockIdx.y * 128;
    if (row0 >= cnt) return;
    int nt = blockIdx.x * 128;

    __shared__ __align__(16) u16 As[128 * 64];
    __shared__ __align__(16) u16 Bs[128 * 64];

    int tid = threadIdx.x;
    int wave = tid >> 6, lane = tid & 63;

    const u16 *gA[4], *gB[4];
    u16 *lA[4], *lB[4];
    const size_t eNK = (size_t)e * HID * INTER_;
#pragma unroll
    for (int is = 0; is < 4; is++) {
        int c = wave * 4 + is;
        int r = c * 8 + (lane >> 3);
        int sg = (lane & 7) ^ (r & 7);
        int mr = row0 + r; if (mr > cnt - 1) mr = cnt - 1;
        gA[is] = A + (size_t)(off + mr) * INTER_ + sg * 8;
        gB[is] = Bt + eNK + (size_t)(nt + r) * INTER_ + sg * 8;
        lA[is] = As + c * 512;
        lB[is] = Bs + c * 512;
    }

    int wr = (wave >> 1) * 64, wc = (wave & 1) * 64;
    int fm = lane & 15, quad = lane >> 4;

    f32x4 acc[4][4];
#pragma unroll
    for (int i = 0; i < 4; i++)
#pragma unroll
        for (int j = 0; j < 4; j++) acc[i][j] = (f32x4){0.f, 0.f, 0.f, 0.f};

    int kend = ks * 1024 + 1024;
    for (int kb = ks * 1024; kb < kend; kb += 64) {
#pragma unroll
        for (int is = 0; is < 4; is++) {
            gl_lds16(gA[is] + kb, lA[is]);
            gl_lds16(gB[is] + kb, lB[is]);
        }
        __syncthreads();
#pragma unroll
        for (int step = 0; step < 2; step++) {
            int f = step * 4 + quad;
            s16x8 af[4], bfr[4];
#pragma unroll
            for (int i = 0; i < 4; i++) {
                int R = wr + i * 16 + fm;
                af[i] = *(const s16x8*)&As[R * 64 + ((f ^ (R & 7)) * 8)];
            }
#pragma unroll
            for (int j = 0; j < 4; j++) {
                int R = wc + j * 16 + fm;
                bfr[j] = *(const s16x8*)&Bs[R * 64 + ((f ^ (R & 7)) * 8)];
            }
#pragma unroll
            for (int i = 0; i < 4; i++)
#pragma unroll
                for (int j = 0; j < 4; j++)
                    acc[i][j] = __builtin_amdgcn_mfma_f32_16x16x32_bf16(af[i], bfr[j], acc[i][j], 0, 0, 0);
        }
        __syncthreads();
    }

    int r4 = quad * 4, cc = lane & 15;
    float* yout = ypart + (size_t)ks * NPAIR * HID;
#pragma unroll
    for (int i = 0; i < 4; i++) {
#pragma unroll
        for (int reg = 0; reg < 4; reg++) {
            int rr = wr + i * 16 + r4 + reg;
            if (row0 + rr < cnt) {
                size_t slot = (size_t)(off + row0 + rr);
#pragma unroll
                for (int j = 0; j < 4; j++) {
                    int col = nt + wc + j * 16 + cc;
                    yout[slot * HID + col] = acc[i][j][reg];
                }
            }
        }
    }
}

// ---------------- weighted combine (sums the two split-K partials) ----------------
__global__ void combine_kernel(const float* __restrict__ y0, const float* __restrict__ y1,
                               const int* __restrict__ pair_slot,
                               const float* __restrict__ tokW, float* __restrict__ out) {
    int i = blockIdx.x * 256 + threadIdx.x;
    int t = i >> 8;
    int h4 = i & 255;
    int s0 = pair_slot[2 * t], s1 = pair_slot[2 * t + 1];
    float w0 = tokW[2 * t], w1 = tokW[2 * t + 1];
    float4 a0 = ((const float4*)y0)[(size_t)s0 * 256 + h4];
    float4 a1 = ((const float4*)y1)[(size_t)s0 * 256 + h4];
    float4 b0 = ((const float4*)y0)[(size_t)s1 * 256 + h4];
    float4 b1 = ((const float4*)y1)[(size_t)s1 * 256 + h4];
    float4 r;
    r.x = w0 * (a0.x + a1.x) + w1 * (b0.x + b1.x);
    r.y = w0 * (a0.y + a1.y) + w1 * (b0.y + b1.y);
    r.z = w0 * (a0.z + a1.z) + w1 * (b0.z + b1.z);
    r.w = w0 * (a0.w + a1.w) + w1 * (b0.w + b1.w);
    ((float4*)out)[i] = r;
}

extern "C" void kernel_launch(void* const* d_in, const int* in_sizes, int n_in,
                              void* d_out, int out_size, void* d_ws, size_t ws_size,
                              hipStream_t stream) {
    (void)in_sizes; (void)n_in; (void)out_size; (void)ws_size;
    const float* x   = (const float*)d_in[0];
    const float* rl  = (const float*)d_in[1];
    const float* wi0 = (const float*)d_in[2];
    const float* wi1 = (const float*)d_in[3];
    const float* wo  = (const float*)d_in[4];
    float* out = (float*)d_out;

    char* p = (char*)d_ws;
    auto alloc = [&](size_t bytes) -> void* {
        void* r = (void*)p;
        p += (bytes + 255) & ~(size_t)255;
        return r;
    };
    u16* xb   = (u16*)alloc((size_t)T_TOKENS * HID * 2);          // 4 MB
    u16* wt0  = (u16*)alloc((size_t)NE * HID * INTER_ * 2);       // 32 MB  [E][I][H]
    u16* wt1  = (u16*)alloc((size_t)NE * HID * INTER_ * 2);       // 32 MB
    u16* wto  = (u16*)alloc((size_t)NE * HID * INTER_ * 2);       // 32 MB  [E][H][I]
    u16* intr = (u16*)alloc((size_t)NPAIR * INTER_ * 2);          // 16 MB
    float* ypart = (float*)alloc((size_t)2 * NPAIR * HID * 4);    // 32 MB
    int* offs     = (int*)alloc((NE + 1) * sizeof(int));
    int* pair_tok = (int*)alloc(NPAIR * sizeof(int));
    float* pair_w = (float*)alloc(NPAIR * sizeof(float));
    int* pair_slot= (int*)alloc(NPAIR * sizeof(int));
    float* tokW   = (float*)alloc(NPAIR * sizeof(float));

    route_all<<<1, 256, 0, stream>>>(rl, offs, pair_tok, pair_w, pair_slot, tokW);
    cvt_x_kernel<<<T_TOKENS * HID / 4 / 256, 256, 0, stream>>>(x, xb);
    transpose_all<<<dim3(128, 24), 256, 0, stream>>>(wi0, wi1, wo, wt0, wt1, wto);

    dim3 g1(INTER_ / 128, 16, NE);
    fused_up_kernel<<<g1, 256, 0, stream>>>(xb, wt0, wt1, pair_tok, offs, intr);
    dim3 g2(HID / 128, 16, NE * 2);
    down_kernel<<<g2, 256, 0, stream>>>(intr, wto, offs, ypart);
    combine_kernel<<<T_TOKENS * HID / 4 / 256, 256, 0, stream>>>(
        ypart, ypart + (size_t)NPAIR * HID, pair_slot, tokW, out);
}